// Round 7
// baseline (732.116 us; speedup 1.0000x reference)
//
#include <hip/hip_runtime.h>
#include <hip/hip_cooperative_groups.h>
namespace cg = cooperative_groups;

#define N_NODES 50000
#define N_EDGES 800000
#define NEG_SLOPE 0.2f
#define BN_EPS  1e-5f

#define CHUNKS 256            // edge chunks for counting sort
#define EDGES_PER_CHUNK 3125  // 256*3125 = 800000 exactly
#define NCOARSE 1024          // coarse buckets = dst>>6
#define NBUCKET 782           // ceil(50000/64) live buckets
#define BNR 16                // rows of spread BN accumulators

typedef short bf16x8 __attribute__((ext_vector_type(8)));
typedef float floatx4 __attribute__((ext_vector_type(4)));

__device__ inline ushort f2bf(float f) {
    union { float f; unsigned u; } v; v.f = f;
    unsigned r = v.u + 0x7fff + ((v.u >> 16) & 1);
    return (ushort)(r >> 16);
}
__device__ inline float bf2f(ushort h) {
    union { unsigned u; float f; } v; v.u = ((unsigned)h) << 16;
    return v.f;
}

// ---------------------------------------------------------------------------
// Cooperative CSR build: count(+Wt transpose, +BN zero) -> per-bucket scan ->
// bucket-base scan -> bucket scatter -> per-bucket CSR build. One dispatch,
// grid.sync() between phases. 1024 blocks x 256 threads (co-resident: ~4KB
// LDS, low VGPR). LDS atomics only; no global atomics.
// ---------------------------------------------------------------------------
__global__ __launch_bounds__(256) void csr_coop_kernel(const int* __restrict__ ei,
                                                       const float* __restrict__ W,
                                                       ushort* __restrict__ Wtb,
                                                       int* __restrict__ counts,
                                                       int* __restrict__ blocksum,
                                                       int* __restrict__ blockbase,
                                                       uint* __restrict__ tmp,
                                                       int* __restrict__ offsets,
                                                       int* __restrict__ csr_src,
                                                       float* __restrict__ gsum2d,
                                                       float* __restrict__ gsq2d)
{
    cg::grid_group grid = cg::this_grid();
    __shared__ int sh[NCOARSE];
    __shared__ int sh2[64];
    __shared__ int sh3[64];
    const int t = threadIdx.x;
    const int b = blockIdx.x;

    // ---- phase 0: count hist (0..255) | Wt transpose (256..511) | BN zero ----
    if (b < CHUNKS) {
        for (int j = t; j < NCOARSE; j += 256) sh[j] = 0;
        __syncthreads();
        const int e0 = b * EDGES_PER_CHUNK;
        for (int e = e0 + t; e < e0 + EDGES_PER_CHUNK; e += 256)
            atomicAdd(&sh[ei[N_EDGES + e] >> 6], 1);
        __syncthreads();
        for (int j = t; j < NCOARSE; j += 256)
            counts[j * CHUNKS + b] = sh[j];   // bucket-major for the scan
    } else if (b < 2 * CHUNKS) {
        const int n = b - CHUNKS;             // output col
        Wtb[n * 256 + t] = f2bf(W[t * 256 + n]);
    } else if (b < 2 * CHUNKS + 2 * BNR) {
        const int i = (b - 2 * CHUNKS) * 256 + t;   // 0..8191
        if (i < BNR * 256) gsum2d[i] = 0.f;
        else               gsq2d[i - BNR * 256] = 0.f;
    }
    grid.sync();

    // ---- phase 1: per-bucket exclusive scan (block b = bucket b) ----
    {
        const int i = b * CHUNKS + t;
        const int v = counts[i];
        sh[t] = v;
        __syncthreads();
#pragma unroll
        for (int off = 1; off < 256; off <<= 1) {
            const int u = (t >= off) ? sh[t - off] : 0;
            __syncthreads();
            sh[t] += u;
            __syncthreads();
        }
        counts[i] = sh[t] - v;   // bucket-local exclusive
        if (t == 255) blocksum[b] = sh[255];
    }
    grid.sync();

    // ---- phase 2: block 0 scans blocksum[1024] -> blockbase ----
    if (b == 0) {
        int v4[4], loc[4], tot = 0;
#pragma unroll
        for (int j = 0; j < 4; ++j) {
            v4[j] = blocksum[t * 4 + j];
            loc[j] = tot;
            tot += v4[j];
        }
        sh[t] = tot;
        __syncthreads();
#pragma unroll
        for (int off = 1; off < 256; off <<= 1) {
            const int u = (t >= off) ? sh[t - off] : 0;
            __syncthreads();
            sh[t] += u;
            __syncthreads();
        }
        const int base = sh[t] - tot;
#pragma unroll
        for (int j = 0; j < 4; ++j) blockbase[t * 4 + j] = base + loc[j];
    }
    grid.sync();

    // ---- phase 3: bucket-partitioned scatter (blocks 0..255) ----
    if (b < CHUNKS) {
        for (int u = t; u < NCOARSE; u += 256)
            sh[u] = counts[u * CHUNKS + b] + blockbase[u];
        __syncthreads();
        const int e0 = b * EDGES_PER_CHUNK;
        for (int e = e0 + t; e < e0 + EDGES_PER_CHUNK; e += 256) {
            const int src = ei[e];
            const int dst = ei[N_EDGES + e];
            const int pos = atomicAdd(&sh[dst >> 6], 1);
            tmp[pos] = ((uint)src << 6) | (uint)(dst & 63);
        }
    }
    grid.sync();

    // ---- phase 4: per-bucket CSR build (blocks 0..NBUCKET-1) ----
    if (b < NBUCKET) {
        const int start = blockbase[b];
        const int end   = blockbase[b + 1];
        if (t < 64) sh[t] = 0;
        __syncthreads();
        for (int e = start + t; e < end; e += 256)
            atomicAdd(&sh[tmp[e] & 63], 1);
        __syncthreads();
        const int v = (t < 64) ? sh[t] : 0;
        if (t < 64) sh2[t] = v;
        __syncthreads();
#pragma unroll
        for (int off = 1; off < 64; off <<= 1) {
            int u = 0;
            if (t < 64 && t >= off) u = sh2[t - off];
            __syncthreads();
            if (t < 64) sh2[t] += u;
            __syncthreads();
        }
        if (t < 64) {
            const int excl = start + sh2[t] - v;
            sh3[t] = excl;
            const int node = b * 64 + t;
            if (node < N_NODES) offsets[node] = excl;
        }
        __syncthreads();
        for (int e = start + t; e < end; e += 256) {
            const uint p = tmp[e];
            const int pos = atomicAdd(&sh3[p & 63], 1);
            csr_src[pos] = (int)(p >> 6);
        }
    }
    if (b == 0 && t == 0) offsets[N_NODES] = N_EDGES;
}

// ---------------------------------------------------------------------------
// MFMA GEMM (fused fp32->bf16 convert of A in staging):
// xb[M,256] = bf16( feature @ W ), 128x128 tile, 4 waves of 64x64.
// Epilogue: per-node attention logits s,d (16-lane shuffle reduce) and
// PERMUTED xb stores: within each 64-col head block, position = l16*4 + ni
// (true col = ni*16 + l16) -> coalesced ushort4 stores.
// ---------------------------------------------------------------------------
#define LDSTRIDE 40  // 32 + 8 pad: 2-way max bank aliasing (free)
__global__ __launch_bounds__(256) void gemm_kernel(const float* __restrict__ A,
                                                   const ushort* __restrict__ Bt,
                                                   const float* __restrict__ att_src,
                                                   const float* __restrict__ att_dst,
                                                   ushort* __restrict__ Xb,
                                                   float* __restrict__ s,
                                                   float* __restrict__ d)
{
    __shared__ ushort As[128 * LDSTRIDE];
    __shared__ ushort Bs[128 * LDSTRIDE];
    const int tid = threadIdx.x;
    const int lane = tid & 63;
    const int wid = tid >> 6;
    const int wm = wid & 1, wn = wid >> 1;
    const int row0 = blockIdx.y * 128;
    const int col0 = blockIdx.x * 128;

    floatx4 acc[4][4] = {};  // [mi][ni]

    const int lr = tid >> 2;        // 0..63 (row base)
    const int lk = (tid & 3) * 8;   // 0,8,16,24 (k elem offset)

    for (int k0 = 0; k0 < 256; k0 += 32) {
#pragma unroll
        for (int r = 0; r < 2; ++r) {
            const int row = lr + r * 64;
            const int grow = row0 + row;
            union { ushort u[8]; ulonglong2 v; } cv;
            if (grow < N_NODES) {
                const float4 f0 = *(const float4*)(A + (size_t)grow * 256 + k0 + lk);
                const float4 f1 = *(const float4*)(A + (size_t)grow * 256 + k0 + lk + 4);
                cv.u[0] = f2bf(f0.x); cv.u[1] = f2bf(f0.y);
                cv.u[2] = f2bf(f0.z); cv.u[3] = f2bf(f0.w);
                cv.u[4] = f2bf(f1.x); cv.u[5] = f2bf(f1.y);
                cv.u[6] = f2bf(f1.z); cv.u[7] = f2bf(f1.w);
            } else {
                cv.v = ulonglong2{0ull, 0ull};
            }
            *(ulonglong2*)(As + row * LDSTRIDE + lk) = cv.v;
            const ulonglong2 bv = *(const ulonglong2*)(Bt + (size_t)(col0 + row) * 256 + k0 + lk);
            *(ulonglong2*)(Bs + row * LDSTRIDE + lk) = bv;
        }
        __syncthreads();
        const int quad = lane >> 4;
        const int l16 = lane & 15;
        bf16x8 afrag[4], bfrag[4];
#pragma unroll
        for (int mi = 0; mi < 4; ++mi)
            afrag[mi] = *(const bf16x8*)(As + (wm * 64 + mi * 16 + l16) * LDSTRIDE + quad * 8);
#pragma unroll
        for (int ni = 0; ni < 4; ++ni)
            bfrag[ni] = *(const bf16x8*)(Bs + (wn * 64 + ni * 16 + l16) * LDSTRIDE + quad * 8);
#pragma unroll
        for (int mi = 0; mi < 4; ++mi)
#pragma unroll
            for (int ni = 0; ni < 4; ++ni)
                acc[mi][ni] = __builtin_amdgcn_mfma_f32_16x16x32_bf16(afrag[mi], bfrag[ni], acc[mi][ni], 0, 0, 0);
        __syncthreads();
    }

    const int quad = lane >> 4;
    const int l16 = lane & 15;
    const int head = (col0 + wn * 64) >> 6;  // wave's 64 cols = one head
    float as_l[4], ad_l[4];
#pragma unroll
    for (int ni = 0; ni < 4; ++ni) {
        const int ch = head * 64 + ni * 16 + l16;  // true channel
        as_l[ni] = att_src[ch];
        ad_l[ni] = att_dst[ch];
    }
#pragma unroll
    for (int mi = 0; mi < 4; ++mi) {
#pragma unroll
        for (int r = 0; r < 4; ++r) {
            const int grow = row0 + wm * 64 + mi * 16 + quad * 4 + r;
            const bool ok = grow < N_NODES;
            float vs = 0.f, vd = 0.f;
            ushort4 o;
#pragma unroll
            for (int ni = 0; ni < 4; ++ni) {
                const float v = acc[mi][ni][r];
                vs += v * as_l[ni];
                vd += v * ad_l[ni];
                ((ushort*)&o)[ni] = f2bf(v);
            }
            if (ok)  // permuted: pos within head block = l16*4 + ni
                *(ushort4*)(Xb + (size_t)grow * 256 + head * 64 + l16 * 4) = o;
#pragma unroll
            for (int m = 8; m >= 1; m >>= 1) {
                vs += __shfl_xor(vs, m);
                vd += __shfl_xor(vd, m);
            }
            if (l16 == 0 && ok) {
                s[grow * 4 + head] = vs;
                d[grow * 4 + head] = vd;
            }
        }
    }
}

// ---------------------------------------------------------------------------
// Aggregate + fused BN partial stats. One wave per node (grid covers exactly
// 50000); lane l owns permuted positions [4l,4l+4); head = l>>4. Edge loop
// unrolled x8 for gather ILP. Block reduces its 4 nodes' (rounded) h values
// per channel in LDS, then one atomicAdd pair per thread into spread
// accumulators gsum2d/gsq2d[BNR][256] (~780 adds per address).
// ---------------------------------------------------------------------------
__global__ __launch_bounds__(256) void aggregate_kernel(const ushort* __restrict__ xb,
                                                        const float* __restrict__ s,
                                                        const float* __restrict__ d,
                                                        const int* __restrict__ offsets,
                                                        const int* __restrict__ csr_src,
                                                        ushort* __restrict__ hagg,
                                                        float* __restrict__ gsum2d,
                                                        float* __restrict__ gsq2d)
{
    __shared__ float s1[4][256];
    __shared__ float s2[4][256];
    const int wid = threadIdx.x >> 6;
    const int lane = threadIdx.x & 63;
    const int n = blockIdx.x * 4 + wid;   // always < 50000
    const int h = lane >> 4;
    const float dn = d[n * 4 + h];
    const float sn = s[n * 4 + h];
    const ushort4 xr = *(const ushort4*)(xb + (size_t)n * 256 + lane * 4);
    float eself = sn + dn;
    eself = eself >= 0.f ? eself : NEG_SLOPE * eself;
    const float pself = __expf(eself);
    float den = pself;
    float a0 = pself * bf2f(xr.x), a1 = pself * bf2f(xr.y);
    float a2 = pself * bf2f(xr.z), a3 = pself * bf2f(xr.w);
    const int e0 = offsets[n];
    const int e1 = offsets[n + 1];
    int e = e0;
    for (; e + 8 <= e1; e += 8) {
        int si[8];
        float lg[8];
        ushort4 xv[8];
#pragma unroll
        for (int j = 0; j < 8; ++j) si[j] = csr_src[e + j];
#pragma unroll
        for (int j = 0; j < 8; ++j) lg[j] = s[si[j] * 4 + h] + dn;
#pragma unroll
        for (int j = 0; j < 8; ++j)
            xv[j] = *(const ushort4*)(xb + (size_t)si[j] * 256 + lane * 4);
#pragma unroll
        for (int j = 0; j < 8; ++j) {
            float l = lg[j];
            l = l >= 0.f ? l : NEG_SLOPE * l;
            const float p = __expf(l);
            den += p;
            a0 += p * bf2f(xv[j].x);
            a1 += p * bf2f(xv[j].y);
            a2 += p * bf2f(xv[j].z);
            a3 += p * bf2f(xv[j].w);
        }
    }
    for (; e < e1; ++e) {
        const int src = csr_src[e];
        float ee = s[src * 4 + h] + dn;
        ee = ee >= 0.f ? ee : NEG_SLOPE * ee;
        const float pe = __expf(ee);
        const ushort4 xs = *(const ushort4*)(xb + (size_t)src * 256 + lane * 4);
        a0 += pe * bf2f(xs.x); a1 += pe * bf2f(xs.y);
        a2 += pe * bf2f(xs.z); a3 += pe * bf2f(xs.w);
        den += pe;
    }
    const float inv = 1.0f / den;
    ushort4 o;
    o.x = f2bf(a0 * inv); o.y = f2bf(a1 * inv);
    o.z = f2bf(a2 * inv); o.w = f2bf(a3 * inv);
    *(ushort4*)(hagg + (size_t)n * 256 + lane * 4) = o;
    // BN partials on the rounded (bf16) values, matching what finalize reads
    const float v0 = bf2f(o.x), v1 = bf2f(o.y), v2 = bf2f(o.z), v3 = bf2f(o.w);
    s1[wid][lane * 4 + 0] = v0;      s2[wid][lane * 4 + 0] = v0 * v0;
    s1[wid][lane * 4 + 1] = v1;      s2[wid][lane * 4 + 1] = v1 * v1;
    s1[wid][lane * 4 + 2] = v2;      s2[wid][lane * 4 + 2] = v2 * v2;
    s1[wid][lane * 4 + 3] = v3;      s2[wid][lane * 4 + 3] = v3 * v3;
    __syncthreads();
    const int t = threadIdx.x;
    const float ps = s1[0][t] + s1[1][t] + s1[2][t] + s1[3][t];
    const float pq = s2[0][t] + s2[1][t] + s2[2][t] + s2[3][t];
    const int row = blockIdx.x & (BNR - 1);
    atomicAdd(&gsum2d[row * 256 + t], ps);
    atomicAdd(&gsq2d[row * 256 + t], pq);
}

// ---------------------------------------------------------------------------
// Finalize (fused bn_final): reduce BNR-row BN partials (L2-hot) into LDS
// mean/rstd once per block, then normalize+ELU+residual. Reads hagg permuted
// (ushort4 coalesced); writes d_out in TRUE layout via 4 per-lane scalar
// stores (16-element runs -> coalesced 64B segments).
// ---------------------------------------------------------------------------
__global__ __launch_bounds__(256) void finalize_kernel(const float* __restrict__ feature,
                                                       const ushort* __restrict__ hagg,
                                                       const float* __restrict__ gsum2d,
                                                       const float* __restrict__ gsq2d,
                                                       const float* __restrict__ gamma,
                                                       const float* __restrict__ beta,
                                                       float* __restrict__ out)
{
    __shared__ float meanL[256], rstdL[256];
    const int t = threadIdx.x;
    float ms = 0.f, qs = 0.f;
#pragma unroll
    for (int r = 0; r < BNR; ++r) {
        ms += gsum2d[r * 256 + t];
        qs += gsq2d[r * 256 + t];
    }
    const float mean = ms * (1.0f / N_NODES);
    const float var = qs * (1.0f / N_NODES) - mean * mean;
    meanL[t] = mean;
    rstdL[t] = rsqrtf(var + BN_EPS);
    __syncthreads();

    const int wid = threadIdx.x >> 6;
    const int lane = threadIdx.x & 63;
    const int wgid = blockIdx.x * 4 + wid;   // 0..12499
    const int hblk = lane >> 4;
    const int l16 = lane & 15;

    float meanv[4], scalev[4], betav[4];
    int tc[4];
#pragma unroll
    for (int j = 0; j < 4; ++j) {
        const int p = lane * 4 + j;                 // permuted channel
        tc[j] = hblk * 64 + j * 16 + l16;           // true channel
        meanv[j] = meanL[p];
        scalev[j] = gamma[tc[j]] * rstdL[p];
        betav[j] = beta[tc[j]];
    }
#pragma unroll
    for (int rr = 0; rr < 4; ++rr) {
        const int n = wgid * 4 + rr;
        const ushort4 hv = *(const ushort4*)(hagg + (size_t)n * 256 + lane * 4);
        const float hvf[4] = {bf2f(hv.x), bf2f(hv.y), bf2f(hv.z), bf2f(hv.w)};
#pragma unroll
        for (int j = 0; j < 4; ++j) {
            float r = (hvf[j] - meanv[j]) * scalev[j] + betav[j];
            r = r > 0.f ? r : expm1f(r);
            out[(size_t)n * 256 + tc[j]] = r + feature[(size_t)n * 256 + tc[j]];
        }
    }
}

// ---------------------------------------------------------------------------
extern "C" void kernel_launch(void* const* d_in, const int* in_sizes, int n_in,
                              void* d_out, int out_size, void* d_ws, size_t ws_size,
                              hipStream_t stream)
{
    const float* feature = (const float*)d_in[0];
    const int*   ei      = (const int*)d_in[1];
    const float* W       = (const float*)d_in[2];
    const float* att_src = (const float*)d_in[3];
    const float* att_dst = (const float*)d_in[4];
    // d_in[5] = bias: cancels inside batchnorm, unused
    const float* gamma   = (const float*)d_in[6];
    const float* beta    = (const float*)d_in[7];
    float* out = (float*)d_out;

    char* w = (char*)d_ws;
    auto carve = [&](size_t bytes) {
        char* p = w;
        w += (bytes + 255) & ~(size_t)255;
        return p;
    };
    ushort* Wtb      = (ushort*)carve((size_t)256 * 256 * 2);
    ushort* xb       = (ushort*)carve((size_t)N_NODES * 256 * 2);
    ushort* hagg     = (ushort*)carve((size_t)N_NODES * 256 * 2);
    float*  s        = (float*)carve((size_t)N_NODES * 4 * 4);
    float*  dv       = (float*)carve((size_t)N_NODES * 4 * 4);
    int*    counts   = (int*)carve((size_t)NCOARSE * CHUNKS * 4);  // 1 MB
    int*    offsets  = (int*)carve((size_t)(N_NODES + 1) * 4);
    int*    csr_src  = (int*)carve((size_t)N_EDGES * 4);
    int*    blocksum = (int*)carve((size_t)NCOARSE * 4);
    int*    blockbase= (int*)carve((size_t)NCOARSE * 4);
    float*  gsum2d   = (float*)carve((size_t)BNR * 256 * 4);
    float*  gsq2d    = (float*)carve((size_t)BNR * 256 * 4);
    // tmp (3.2 MB packed edges) aliases hagg: dead until aggregate writes it;
    // csr_coop phase 4 (last tmp reader) completes before aggregate launches.
    uint*   tmp      = (uint*)hagg;

    void* cargs[] = {(void*)&ei, (void*)&W, (void*)&Wtb, (void*)&counts,
                     (void*)&blocksum, (void*)&blockbase, (void*)&tmp,
                     (void*)&offsets, (void*)&csr_src,
                     (void*)&gsum2d, (void*)&gsq2d};
    hipLaunchCooperativeKernel((void*)csr_coop_kernel, dim3(NCOARSE), dim3(256),
                               cargs, 0, stream);
    gemm_kernel<<<dim3(2, 391), 256, 0, stream>>>(feature, Wtb, att_src, att_dst, xb, s, dv);
    aggregate_kernel<<<12500, 256, 0, stream>>>(xb, s, dv, offsets, csr_src, hagg,
                                                gsum2d, gsq2d);
    finalize_kernel<<<3125, 256, 0, stream>>>(feature, hagg, gsum2d, gsq2d, gamma, beta, out);
}